// Round 9
// baseline (447.240 us; speedup 1.0000x reference)
//
#include <hip/hip_runtime.h>

// CombinedLoss: 0.7*MSE + 0.3*mean_b softDTW_gamma.  B=64, T=1024, C=8, fp32.
// R9 = R8 with two deadlock fixes in the self-timed protocol:
//  (1) s_bwd[w] init = 8q+2w-1 (consumer's amin-1) -- R8's 2w-1 deadlocked all
//      q>0 blocks at their first producer credit-wait.
//  (2) forward wait capped at producer's amax (2(g-1)+33) -- R8 spun forever
//      at consumer windows 2g+32/2g+33 (halo there only feeds invalid lane 0).
// Structure: 4 bands x 64 batches = 256 blocks (4 waves), self-timed wave
// pipeline, 34 windows x 32 diagonals per wave. Intra-block: 4-deep LDS window
// ring + acquire/release LDS flags. Cross-block: self-validating u64 tag ring
// in ws (relaxed agent atomics) with 1-window prefetch. t-columns flow via DPP.
// ws: [0,256) mse | [256,320) sdtw | u64 rings @ float-offset 320 (~1.67 MB).

constexpr int TT = 1024;
constexpr float ALPHA_ = 0.7f;
constexpr float FINF = 1000000000.0f;
constexpr int RING = 1088;

__device__ __forceinline__ float shflup1(float old0, float v) {
    return __int_as_float(__builtin_amdgcn_update_dpp(
        __float_as_int(old0), __float_as_int(v), 0x138, 0xf, 0xf, false));
}
__device__ __forceinline__ float rotdn1(float v) {
    return __int_as_float(__builtin_amdgcn_update_dpp(
        0, __float_as_int(v), 0x130, 0xf, 0xf, false));
}

__global__ __launch_bounds__(256) void sdtw_band_kernel(
    const float* __restrict__ pred, const float* __restrict__ target,
    float* __restrict__ ws)
{
    __shared__ float4 s_p4[TT * 2];     // col j: [-2t0..3],[-2t4..7]
    __shared__ float  s_y2[TT];
    __shared__ float  s_ring[4][4][32]; // [wave][window&3][slot k&31]
    __shared__ float  s_scr[96];        // sink for non-lane63 halo writes
    __shared__ float  s_red[4];
    __shared__ int    s_fwd[4];         // highest window produced by wave w
    __shared__ int    s_bwd[4];         // highest window consumed by wave w

    const int blk = blockIdx.x;
    const int b   = blk & 63;                  // batch
    const int q   = blk >> 6;                  // band
    const int tid = threadIdx.x;
    const int l   = tid & 63;
    const int w_  = __builtin_amdgcn_readfirstlane(tid >> 6);
    const int g   = (q << 2) + w_;             // global wave 0..15
    const int gbase = g << 6;
    const int row   = gbase + l;

    const float* pr = pred   + ((size_t)b * TT + row) * 8;
    const float* tr = target + ((size_t)b * TT + row) * 8;
    const float4 pa = ((const float4*)pr)[0];
    const float4 pb = ((const float4*)pr)[1];
    const float4 ma = ((const float4*)tr)[0];
    const float4 mb = ((const float4*)tr)[1];

    float x2 = 0.f, msep = 0.f;
    {
        const float pp[8] = {pa.x,pa.y,pa.z,pa.w,pb.x,pb.y,pb.z,pb.w};
        const float tt[8] = {ma.x,ma.y,ma.z,ma.w,mb.x,mb.y,mb.z,mb.w};
        #pragma unroll
        for (int c = 0; c < 8; ++c) {
            x2 = fmaf(pp[c], pp[c], x2);
            float d = pp[c] - tt[c];
            msep = fmaf(d, d, msep);
        }
    }
    const float* tg = target + (size_t)b * TT * 8;
    #pragma unroll
    for (int c0 = 0; c0 < 4; ++c0) {
        const int col = tid + (c0 << 8);
        const float4 u0 = ((const float4*)(tg + (size_t)col * 8))[0];
        const float4 u1 = ((const float4*)(tg + (size_t)col * 8))[1];
        s_p4[2*col]   = make_float4(-2.f*u0.x, -2.f*u0.y, -2.f*u0.z, -2.f*u0.w);
        s_p4[2*col+1] = make_float4(-2.f*u1.x, -2.f*u1.y, -2.f*u1.z, -2.f*u1.w);
        s_y2[col] = u0.x*u0.x + u0.y*u0.y + u0.z*u0.z + u0.w*u0.w
                  + u1.x*u1.x + u1.y*u1.y + u1.z*u1.z + u1.w*u1.w;
    }
    #pragma unroll
    for (int off = 32; off > 0; off >>= 1) msep += __shfl_down(msep, off, 64);
    if (l == 0) s_red[w_] = msep;
    if (tid < 4) {
        s_fwd[tid] = -1;
        s_bwd[tid] = 8 * q + 2 * tid - 1;   // consumer's amin - 1  [fix 1]
    }
    __syncthreads();                        // ONLY barrier in the kernel
    if (tid == 0) ws[blk] = s_red[0] + s_red[1] + s_red[2] + s_red[3];

    unsigned long long* rings = (unsigned long long*)(ws + 320);
    unsigned long long* pub = rings + (size_t)(q * 64 + b) * RING;       // w_==3,q<3
    unsigned long long* con = rings + (size_t)((q - 1) * 64 + b) * RING; // w_==0,q>0
    const int kb_pub   = 256 * q + 192;
    const int kb_con   = 256 * q - 64;
    const int kmax_con = 256 * q + 1022;

    const float c1 = 7.213475204444817f;     // log2(e)/gamma
    const float c2 = 0.13862943611198906f;   // gamma*ln(2)

    float r1 = FINF, r2 = FINF;
    float tf0=0,tf1=0,tf2=0,tf3=0,tf4=0,tf5=0,tf6=0,tf7=0, y2f=0;
    int jj0 = 0;
    float4 A0 = s_p4[0], B0 = s_p4[1], A1 = s_p4[2], B1 = s_p4[3];
    float ya = s_y2[0], yb = s_y2[1];
    unsigned long long pe1 = 0, pe2 = 0;
    int ppf = 0;

    const int amin = g << 1, amax = amin + 33;   // 34 windows of 32 diags
    const int prodmax = amin + 31;               // = 2(g-1)+33  [fix 2]
    const int klast = gbase + 63 + TT - 1;

    for (int a = amin; a <= amax; ++a) {
        const int k0 = a << 5;
        const int u  = a - amin;                  // 0..33
        const int khi = min(k0 + 31, klast);
        const int ndv = khi - k0;                 // 31 except last window (30)

        // ---- writer credit: never run >3 windows ahead of intra-block reader
        if (w_ < 3) {
            while (__hip_atomic_load(&s_bwd[w_ + 1], __ATOMIC_ACQUIRE,
                       __HIP_MEMORY_SCOPE_WORKGROUP) < a - 3)
                __builtin_amdgcn_s_sleep(1);
        }

        // ---- stage halo (row gbase-1 at diags k0-1+l / k0-2+l) ----
        float hv, hvd;
        if (w_ == 0) {
            if (q == 0) {
                hv  = FINF;
                hvd = (a == 0 && l == 0) ? 0.0f : FINF;
            } else {
                const int kk1 = k0 - 1 + l, kk2 = k0 - 2 + l;
                const int id1 = min(kk1 - kb_con, RING - 1);
                const int id2 = min(kk2 - kb_con, RING - 1);
                const bool n1 = (l < 32) && (kk1 <= kmax_con);
                const bool n2 = (l < 32) && (kk2 <= kmax_con);
                unsigned long long e1, e2;
                if (ppf) { e1 = pe1; e2 = pe2; ppf = 0; }
                else {
                    e1 = __hip_atomic_load(con + id1, __ATOMIC_RELAXED,
                                           __HIP_MEMORY_SCOPE_AGENT);
                    e2 = __hip_atomic_load(con + id2, __ATOMIC_RELAXED,
                                           __HIP_MEMORY_SCOPE_AGENT);
                }
                while (!__all(((!n1) | ((int)(e1 >> 32) == kk1)) &
                              ((!n2) | ((int)(e2 >> 32) == kk2)))) {
                    e1 = __hip_atomic_load(con + id1, __ATOMIC_RELAXED,
                                           __HIP_MEMORY_SCOPE_AGENT);
                    e2 = __hip_atomic_load(con + id2, __ATOMIC_RELAXED,
                                           __HIP_MEMORY_SCOPE_AGENT);
                }
                hv  = n1 ? __uint_as_float((unsigned)e1) : FINF;
                hvd = n2 ? __uint_as_float((unsigned)e2) : FINF;
                if (a < amax) {               // prefetch next window's entries
                    const int kn = k0 + 32;
                    pe1 = __hip_atomic_load(con + min(kn - 1 + l - kb_con, RING - 1),
                                            __ATOMIC_RELAXED, __HIP_MEMORY_SCOPE_AGENT);
                    pe2 = __hip_atomic_load(con + min(kn - 2 + l - kb_con, RING - 1),
                                            __ATOMIC_RELAXED, __HIP_MEMORY_SCOPE_AGENT);
                    ppf = 1;
                }
            }
        } else {
            const int need_f = min(a, prodmax);   // [fix 2]
            while (__hip_atomic_load(&s_fwd[w_ - 1], __ATOMIC_ACQUIRE,
                       __HIP_MEMORY_SCOPE_WORKGROUP) < need_f)
                __builtin_amdgcn_s_sleep(1);
            const int kk1 = k0 - 1 + l, kk2 = k0 - 2 + l;
            hv  = s_ring[w_ - 1][(kk1 >> 5) & 3][kk1 & 31];
            hvd = s_ring[w_ - 1][(kk2 >> 5) & 3][kk2 & 31];
            if (l == 0)                        // credit back (after reads drain)
                __hip_atomic_store(&s_bwd[w_], a, __ATOMIC_RELEASE,
                                   __HIP_MEMORY_SCOPE_WORKGROUP);
        }
        float* wrp = (l == 63) ? &s_ring[w_][a & 3][0] : &s_scr[l];

        auto diag = [&](int d, bool edge_) {
            tf0 = shflup1(A0.x, tf0); tf1 = shflup1(A0.y, tf1);
            tf2 = shflup1(A0.z, tf2); tf3 = shflup1(A0.w, tf3);
            tf4 = shflup1(B0.x, tf4); tf5 = shflup1(B0.y, tf5);
            tf6 = shflup1(B0.z, tf6); tf7 = shflup1(B0.w, tf7);
            y2f = shflup1(ya, y2f);
            const float up   = shflup1(hv,  r1);
            const float dg   = shflup1(hvd, r2);
            const float left = r1;
            hv = rotdn1(hv); hvd = rotdn1(hvd);
            A0 = A1; B0 = B1; ya = yb;
            jj0 = min(jj0 + 1, TT - 1);
            const int jn = min(jj0 + 1, TT - 1);
            A1 = s_p4[2*jn]; B1 = s_p4[2*jn + 1]; yb = s_y2[jn];
            float acc = x2 + y2f;
            acc = fmaf(pa.x, tf0, acc); acc = fmaf(pa.y, tf1, acc);
            acc = fmaf(pa.z, tf2, acc); acc = fmaf(pa.w, tf3, acc);
            acc = fmaf(pb.x, tf4, acc); acc = fmaf(pb.y, tf5, acc);
            acc = fmaf(pb.z, tf6, acc); acc = fmaf(pb.w, tf7, acc);
            const float m  = fminf(fminf(up, left), dg);
            const float M  = fmaxf(fmaxf(up, left), dg);
            const float md = __builtin_amdgcn_fmed3f(up, left, dg);
            const float mc = m * c1;
            const float e1 = __builtin_amdgcn_exp2f(fmaf(md, -c1, mc));
            const float e2 = __builtin_amdgcn_exp2f(fmaf(M,  -c1, mc));
            const float lg = __builtin_amdgcn_logf(1.0f + (e1 + e2));
            float rn = acc + fmaf(-c2, lg, m);
            if (edge_) {
                const int jj = k0 + d - row;
                rn = ((unsigned)jj < (unsigned)TT) ? rn : FINF;
            }
            r2 = r1; r1 = rn;
            wrp[d] = rn;
        };

        if (u >= 2 && u <= 31) {                 // interior: all lanes valid
            #pragma unroll 8
            for (int d = 0; d < 32; ++d) diag(d, false);
        } else {                                 // edge windows: clamp+select
            for (int d = 0; d <= ndv; ++d) diag(d, true);
        }

        // ---- publish window a ----
        if (w_ < 3) {
            if (l == 0)
                __hip_atomic_store(&s_fwd[w_], a, __ATOMIC_RELEASE,
                                   __HIP_MEMORY_SCOPE_WORKGROUP);
        } else if (q < 3) {
            if (l <= ndv) {
                const int kk = k0 + l;
                const unsigned long long ev =
                    ((unsigned long long)(unsigned)kk << 32) |
                    (unsigned long long)__float_as_uint(s_ring[3][a & 3][l]);
                __hip_atomic_store(pub + (kk - kb_pub), ev,
                                   __ATOMIC_RELAXED, __HIP_MEMORY_SCOPE_AGENT);
            }
        }
    }
    if (q == 3 && tid == 255) ws[256 + b] = r1;  // r_{2T-2}(T-1)
}

__global__ __launch_bounds__(256) void finalize2_kernel(
    const float* __restrict__ ws, float* __restrict__ out)
{
    __shared__ float sm[4], ss[4];
    const int tid = threadIdx.x, l = tid & 63, w = tid >> 6;
    float m  = ws[tid];
    float sd = (tid < 64) ? ws[256 + tid] : 0.f;
    #pragma unroll
    for (int off = 32; off > 0; off >>= 1) {
        m  += __shfl_down(m,  off, 64);
        sd += __shfl_down(sd, off, 64);
    }
    if (l == 0) { sm[w] = m; ss[w] = sd; }
    __syncthreads();
    if (tid == 0) {
        float M = sm[0] + sm[1] + sm[2] + sm[3];
        float S = ss[0] + ss[1] + ss[2] + ss[3];
        out[0] = ALPHA_ * (M / 524288.0f) + (1.0f - ALPHA_) * (S / 64.0f);
    }
}

extern "C" void kernel_launch(void* const* d_in, const int* in_sizes, int n_in,
                              void* d_out, int out_size, void* d_ws, size_t ws_size,
                              hipStream_t stream) {
    const float* pred   = (const float*)d_in[0];
    const float* target = (const float*)d_in[1];
    float* ws  = (float*)d_ws;
    float* out = (float*)d_out;

    sdtw_band_kernel<<<256, 256, 0, stream>>>(pred, target, ws);
    finalize2_kernel<<<1, 256, 0, stream>>>(ws, out);
}